// Round 2
// baseline (2214.570 us; speedup 1.0000x reference)
//
#include <hip/hip_runtime.h>
#include <math.h>

#define N_NODES 50000
#define N_EDGES 500000

__device__ __forceinline__ float gelu_tanh(float x) {
    const float k0 = 0.7978845608028654f;
    const float k1 = 0.044715f;
    float inner = k0 * (x + k1 * x * x * x);
    return 0.5f * x * (1.0f + tanhf(inner));
}

// K1: per-node lift. feat_s (N,32), feat_v (N,32,3) -> ws ; a*self -> d_out (all 128)
__global__ void node_pre(const float* __restrict__ node_input,
                         const float* __restrict__ W1_s,
                         const float* __restrict__ W1_v,
                         float* __restrict__ feat_s,
                         float* __restrict__ feat_v,
                         float* __restrict__ out) {
    __shared__ float lWs[32 * 64];
    __shared__ float lWv[32 * 64];
    for (int i = threadIdx.x; i < 2048; i += blockDim.x) {
        lWs[i] = W1_s[i];
        lWv[i] = W1_v[i];
    }
    __syncthreads();
    int n = blockIdx.x * blockDim.x + threadIdx.x;
    if (n >= N_NODES) return;
    const float inv_sqrt_mul = 0.17677669529663687f;  // 1/sqrt(32)
    const float a_mix = 0.9219544457292887f;          // sqrt(0.85)

    float s[32];
#pragma unroll
    for (int u = 0; u < 32; ++u) s[u] = node_input[n * 128 + u];
#pragma unroll 4
    for (int w = 0; w < 64; ++w) {
        float acc = 0.f;
#pragma unroll
        for (int u = 0; u < 32; ++u) acc += s[u] * lWs[u * 64 + w];
        acc *= inv_sqrt_mul;
        if (w < 32) feat_s[n * 32 + w] = acc;
        else        out[n * 128 + (w - 32)] = a_mix * acc;
    }
#pragma unroll
    for (int k = 0; k < 3; ++k) {
        float vk[32];
#pragma unroll
        for (int u = 0; u < 32; ++u) vk[u] = node_input[n * 128 + 32 + u * 3 + k];
#pragma unroll 4
        for (int w = 0; w < 64; ++w) {
            float acc = 0.f;
#pragma unroll
            for (int u = 0; u < 32; ++u) acc += vk[u] * lWv[u * 64 + w];
            acc *= inv_sqrt_mul;
            if (w < 32) feat_v[n * 96 + w * 3 + k] = acc;
            else        out[n * 128 + 32 + (w - 32) * 3 + k] = a_mix * acc;
        }
    }
}

// K2a: histogram of edge_dst
__global__ void hist_kernel(const int* __restrict__ edge_dst, int* __restrict__ counts) {
    int e = blockIdx.x * blockDim.x + threadIdx.x;
    if (e < N_EDGES) atomicAdd(&counts[edge_dst[e]], 1);
}

// K2b: exclusive scan of counts -> offsets (N+1) and cursor (N). Single block.
__global__ void scan_kernel(const int* __restrict__ counts,
                            int* __restrict__ offsets,
                            int* __restrict__ cursor) {
    const int T = 1024;
    __shared__ int partial[T];
    int t = threadIdx.x;
    const int chunk = (N_NODES + T - 1) / T;  // 49
    int start = t * chunk;
    int end = start + chunk; if (end > N_NODES) end = N_NODES;
    if (start > N_NODES) start = N_NODES;
    int sum = 0;
    for (int i = start; i < end; ++i) sum += counts[i];
    partial[t] = sum;
    __syncthreads();
    // Hillis-Steele inclusive scan
    for (int off = 1; off < T; off <<= 1) {
        int other = (t >= off) ? partial[t - off] : 0;
        __syncthreads();
        partial[t] += other;
        __syncthreads();
    }
    int run = (t == 0) ? 0 : partial[t - 1];
    for (int i = start; i < end; ++i) {
        offsets[i] = run;
        cursor[i] = run;
        run += counts[i];
    }
    if (t == T - 1) offsets[N_NODES] = run;  // == N_EDGES
}

// K2c: scatter packed edge records into dst-sorted order.
// record (16 floats, 64B): [y0,y1x,y1y,y1z | s0..s3 | s4..s7 | src(int), pad x3]
__global__ void scatter_kernel(const int* __restrict__ edge_src,
                               const int* __restrict__ edge_dst,
                               const float* __restrict__ edge_attr,
                               const float* __restrict__ edge_scalars,
                               int* __restrict__ cursor,
                               float* __restrict__ packed) {
    int e = blockIdx.x * blockDim.x + threadIdx.x;
    if (e >= N_EDGES) return;
    int d = edge_dst[e];
    int pos = atomicAdd(&cursor[d], 1);
    float4 a  = *(const float4*)(edge_attr + (size_t)e * 4);
    float4 s0 = *(const float4*)(edge_scalars + (size_t)e * 8);
    float4 s1 = *(const float4*)(edge_scalars + (size_t)e * 8 + 4);
    float4* pf = (float4*)(packed + (size_t)pos * 16);
    pf[0] = a;
    pf[1] = s0;
    pf[2] = s1;
    float4 tail;
    ((int*)&tail)[0] = edge_src[e];
    ((int*)&tail)[1] = 0; ((int*)&tail)[2] = 0; ((int*)&tail)[3] = 0;
    pf[3] = tail;
}

// K3: per-node conv. One 32-lane group per dst node. No atomics.
__global__ void conv_kernel(const float* __restrict__ packed,
                            const int* __restrict__ offsets,
                            const float* __restrict__ M0,
                            const float* __restrict__ M1,
                            const float* __restrict__ Wtp0,
                            const float* __restrict__ Wtp1,
                            const float* __restrict__ Wtp2,
                            const float* __restrict__ Wtp3,
                            const float* __restrict__ W2_s,
                            const float* __restrict__ W2_v,
                            const float* __restrict__ feat_s,
                            const float* __restrict__ feat_v,
                            float* __restrict__ out) {
    __shared__ float lM0[8 * 32];
    __shared__ float lM1[32 * 32];
    __shared__ float lW0[32 * 32];
    __shared__ float lW1[32 * 32];
    __shared__ float lW2[32 * 32];
    __shared__ float lW3[32 * 32];
    __shared__ float lW2s[64 * 32];
    __shared__ float lW2v[64 * 32];
    for (int i = threadIdx.x; i < 256; i += blockDim.x) lM0[i] = M0[i];
    for (int i = threadIdx.x; i < 1024; i += blockDim.x) {
        lM1[i] = M1[i];
        lW0[i] = Wtp0[i];
        lW1[i] = Wtp1[i];
        lW2[i] = Wtp2[i];
        lW3[i] = Wtp3[i];
    }
    for (int i = threadIdx.x; i < 2048; i += blockDim.x) {
        lW2s[i] = W2_s[i];
        lW2v[i] = W2_v[i];
    }
    __syncthreads();

    const int lane = threadIdx.x & 31;
    const int node = (blockIdx.x * blockDim.x + threadIdx.x) >> 5;
    if (node >= N_NODES) return;

    const float inv_sqrt8  = 0.35355339059327373f;
    const float inv_sqrt32 = 0.17677669529663687f;
    const float INV3 = 0.5773502691896258f;  // 1/sqrt(3)

    const int eb = offsets[node];
    const int ee = offsets[node + 1];

    float a0a = 0.f, a0b = 0.f;
    float a1ax = 0.f, a1ay = 0.f, a1az = 0.f;
    float a1bx = 0.f, a1by = 0.f, a1bz = 0.f;

    for (int e = eb; e < ee; ++e) {
        const float* rec = packed + (size_t)e * 16;
        const float y0  = rec[0];
        const float y1x = rec[1];
        const float y1y = rec[2];
        const float y1z = rec[3];
        const int src = ((const int*)rec)[12];

        float t = 0.f;
#pragma unroll
        for (int i = 0; i < 8; ++i) t += rec[4 + i] * lM0[i * 32 + lane];
        t = gelu_tanh(t * inv_sqrt8);
        float h = 0.f;
#pragma unroll
        for (int m = 0; m < 32; ++m) h += __shfl(t, m, 32) * lM1[m * 32 + lane];
        h = gelu_tanh(h * inv_sqrt32);
        float w0 = 0.f, w1 = 0.f, w2 = 0.f, w3 = 0.f;
#pragma unroll
        for (int j = 0; j < 32; ++j) {
            float hj = __shfl(h, j, 32);
            w0 += hj * lW0[j * 32 + lane];
            w1 += hj * lW1[j * 32 + lane];
            w2 += hj * lW2[j * 32 + lane];
            w3 += hj * lW3[j * 32 + lane];
        }
        w0 *= inv_sqrt32; w1 *= inv_sqrt32; w2 *= inv_sqrt32; w3 *= inv_sqrt32;

        const float es  = feat_s[(size_t)src * 32 + lane];
        const float evx = feat_v[(size_t)src * 96 + lane * 3 + 0];
        const float evy = feat_v[(size_t)src * 96 + lane * 3 + 1];
        const float evz = feat_v[(size_t)src * 96 + lane * 3 + 2];
        const float dvy = evx * y1x + evy * y1y + evz * y1z;

        a0a += w0 * es * y0;
        a0b += w3 * dvy * INV3;
        const float w1es = w1 * es;
        const float w2y0 = w2 * y0;
        a1ax += w1es * y1x;
        a1ay += w1es * y1y;
        a1az += w1es * y1z;
        a1bx += w2y0 * evx;
        a1by += w2y0 * evy;
        a1bz += w2y0 * evz;
    }

    // projection: conv = (acc * inv_deg) @ W2 / sqrt(64); out += sqrt(MIX)*conv
    // combined scale:
    const float scale = 0.31622776601683794f * 0.125f * 0.3872983346207417f;

    float cs = 0.f, cvx = 0.f, cvy = 0.f, cvz = 0.f;
#pragma unroll
    for (int j = 0; j < 32; ++j) {
        const float va = __shfl(a0a, j, 32);
        const float vb = __shfl(a0b, j, 32);
        cs += va * lW2s[j * 32 + lane] + vb * lW2s[(32 + j) * 32 + lane];
        const float vax = __shfl(a1ax, j, 32);
        const float vay = __shfl(a1ay, j, 32);
        const float vaz = __shfl(a1az, j, 32);
        const float vbx = __shfl(a1bx, j, 32);
        const float vby = __shfl(a1by, j, 32);
        const float vbz = __shfl(a1bz, j, 32);
        const float wva = lW2v[j * 32 + lane];
        const float wvb = lW2v[(32 + j) * 32 + lane];
        cvx += vax * wva + vbx * wvb;
        cvy += vay * wva + vby * wvb;
        cvz += vaz * wva + vbz * wvb;
    }

    float* o = out + (size_t)node * 128;
    o[lane] += scale * cs;
    o[32 + lane * 3 + 0] += scale * cvx;
    o[32 + lane * 3 + 1] += scale * cvy;
    o[32 + lane * 3 + 2] += scale * cvz;
}

extern "C" void kernel_launch(void* const* d_in, const int* in_sizes, int n_in,
                              void* d_out, int out_size, void* d_ws, size_t ws_size,
                              hipStream_t stream) {
    const float* node_input   = (const float*)d_in[0];
    const float* edge_attr    = (const float*)d_in[1];
    const float* edge_scalars = (const float*)d_in[2];
    const float* W1_s = (const float*)d_in[3];
    const float* W1_v = (const float*)d_in[4];
    const float* M0   = (const float*)d_in[5];
    const float* M1   = (const float*)d_in[6];
    const float* Wtp0 = (const float*)d_in[7];
    const float* Wtp1 = (const float*)d_in[8];
    const float* Wtp2 = (const float*)d_in[9];
    const float* Wtp3 = (const float*)d_in[10];
    const float* W2_s = (const float*)d_in[11];
    const float* W2_v = (const float*)d_in[12];
    const int* edge_src = (const int*)d_in[13];
    const int* edge_dst = (const int*)d_in[14];
    float* out = (float*)d_out;
    float* ws  = (float*)d_ws;

    float* feat_s = ws;                                    // N*32
    float* feat_v = ws + (size_t)N_NODES * 32;             // N*96
    float* packed = ws + (size_t)N_NODES * 128;            // E*16 (64B-aligned records)
    int*   counts  = (int*)(ws + (size_t)N_NODES * 128 + (size_t)N_EDGES * 16);  // N
    int*   offsets = counts + N_NODES;                     // N+1
    int*   cursor  = offsets + N_NODES + 1;                // N
    // total: 50000*128 + 500000*16 + ~150001 ints ~= 58.3 MB

    hipMemsetAsync(counts, 0, N_NODES * sizeof(int), stream);

    node_pre<<<(N_NODES + 255) / 256, 256, 0, stream>>>(node_input, W1_s, W1_v,
                                                        feat_s, feat_v, out);

    hist_kernel<<<(N_EDGES + 255) / 256, 256, 0, stream>>>(edge_dst, counts);
    scan_kernel<<<1, 1024, 0, stream>>>(counts, offsets, cursor);
    scatter_kernel<<<(N_EDGES + 255) / 256, 256, 0, stream>>>(edge_src, edge_dst,
                                                              edge_attr, edge_scalars,
                                                              cursor, packed);

    const int conv_blocks = (N_NODES * 32 + 255) / 256;
    conv_kernel<<<conv_blocks, 256, 0, stream>>>(packed, offsets,
                                                 M0, M1, Wtp0, Wtp1, Wtp2, Wtp3,
                                                 W2_s, W2_v, feat_s, feat_v, out);
}